// Round 7
// baseline (2483.989 us; speedup 1.0000x reference)
//
#include <hip/hip_runtime.h>
#include <float.h>

typedef unsigned int u32;
typedef unsigned long long u64;

// Bb=512, F=16 -> 8192 beam rows, D=128, DH=256, K=4096, A=32, Fo=16, M=2.
// Selection-critical math reproduces numpy's f32 arithmetic bitwise (model):
//  - matmul: per-output sequential f32 FMA over k ascending (sgemm micro-kernel)
//  - np.sum(last axis): 8-accumulator pairwise (n<=128 base case), no FMA
//  - dist/d2 combine: separate f32 mul + f32 sub (ufuncs don't fuse)
//  - all top-k: f32 keys, ties -> lower index (stable, = jax top_k & np)
// The factored-f32 MLP is a prescreen only (top-32 cut, huge margin).

static __device__ __forceinline__ u32 ordu(float f) {
  u32 u = __float_as_uint(f);
  return u ^ (u32)(((int)u >> 31) | (int)0x80000000);
}

// ---------------- prep ----------------

// codebook_rq [4096][128] -> cbT [128][4096]
__global__ __launch_bounds__(256) void k_cbrqT(const float* __restrict__ cbrq,
                                               float* __restrict__ cbT) {
  __shared__ float tile[128 * 33];
  const int k0 = blockIdx.x * 32;
  const int t = threadIdx.x;
#pragma unroll
  for (int rep = 0; rep < 16; ++rep) {
    const int flat = rep * 256 + t;
    const int kk = flat >> 7, d = flat & 127;
    tile[d * 33 + kk] = cbrq[(k0 + kk) * 128 + d];
  }
  __syncthreads();
#pragma unroll
  for (int rep = 0; rep < 16; ++rep) {
    const int flat = rep * 256 + t;
    const int d = flat >> 5, kk = flat & 31;
    cbT[d * 4096 + k0 + kk] = tile[d * 33 + kk];
  }
}

// cb_sq[k] = np.sum(cbrq[k]*cbrq[k]) : exact numpy pairwise-8 emulation.
// Reads via cbT for coalescing (same float values, same d-order).
__global__ __launch_bounds__(256) void k_cbsq(const float* __restrict__ cbT,
                                              float* __restrict__ cb_sq) {
  const int k = blockIdx.x * 256 + threadIdx.x;  // 4096 threads
  float r[8];
#pragma unroll
  for (int j = 0; j < 8; ++j) {
    const float v = cbT[j * 4096 + k];
    r[j] = __fmul_rn(v, v);
  }
  for (int i = 8; i < 128; i += 8) {
#pragma unroll
    for (int j = 0; j < 8; ++j) {
      const float v = cbT[(i + j) * 4096 + k];
      r[j] = __fadd_rn(r[j], __fmul_rn(v, v));
    }
  }
  cb_sq[k] = __fadd_rn(
      __fadd_rn(__fadd_rn(r[0], r[1]), __fadd_rn(r[2], r[3])),
      __fadd_rn(__fadd_rn(r[4], r[5]), __fadd_rn(r[6], r[7])));
}

// xt f32 = x - xhat (single f32 op, as reference)
__global__ __launch_bounds__(256) void k_xt(const float* __restrict__ x,
                                            const float* __restrict__ xhat,
                                            float* __restrict__ xt) {
  const int i = blockIdx.x * 256 + threadIdx.x;  // float4 over 8192*32
  const int row = i >> 5, d4 = i & 31;
  const float4 a = ((const float4*)x)[(row >> 4) * 32 + d4];
  const float4 b = ((const float4*)xhat)[i];
  float4 r;
  r.x = __fsub_rn(a.x, b.x); r.y = __fsub_rn(a.y, b.y);
  r.z = __fsub_rn(a.z, b.z); r.w = __fsub_rn(a.w, b.w);
  ((float4*)xt)[i] = r;
}

// tmp_h[code][j] = seqFMA_d(cb[code][d]*in_w[d][j]) + in_b[j]
__global__ __launch_bounds__(256) void k_codeh(const float* __restrict__ cb,
                                               const float* __restrict__ in_w,
                                               const float* __restrict__ in_b,
                                               float* __restrict__ tmp_h) {
  __shared__ float row[128];
  const int code = blockIdx.x;
  const int t = threadIdx.x;
  if (t < 128) row[t] = cb[code * 128 + t];
  __syncthreads();
  float a = 0.f;
  for (int d = 0; d < 128; ++d) a = __builtin_fmaf(row[d], in_w[d * 256 + t], a);
  tmp_h[code * 256 + t] = __fadd_rn(a, in_b[t]);
}

// prescreen bias prep
__global__ __launch_bounds__(256) void k_biasprep(
    const float* __restrict__ rb_b1, const float* __restrict__ rb_b2,
    const float* __restrict__ rb_w1, const float* __restrict__ out_w,
    const float* __restrict__ out_b, float* __restrict__ bias2v,
    float* __restrict__ biasDv) {
  const int t = threadIdx.x;
  const float* w11 = rb_w1 + 65536;
  float s = rb_b1[256 + t];
  for (int i = 0; i < 256; ++i) s += rb_b2[i] * w11[i * 256 + t];
  bias2v[t] = s;
  if (t < 128) {
    float s2 = out_b[t];
    for (int i = 0; i < 256; ++i)
      s2 += (rb_b2[i] + rb_b2[256 + i]) * out_w[i * 128 + t];
    biasDv[t] = s2;
  }
}

// ---------------- generic f32 GEMM (prescreen precompute only) ----------------
__global__ __launch_bounds__(256, 4) void gemm_f32(
    const float* __restrict__ Am, const float* __restrict__ Bm,
    float* __restrict__ Cm, const int Mi, const int Ni, const int Ki,
    const float* __restrict__ bias, const float* __restrict__ addm) {
  __shared__ float As[16][68];
  __shared__ float Bs[16][68];
  const int m0 = blockIdx.x * 64, n0 = blockIdx.y * 64;
  const int t = threadIdx.x;
  const int tm = (t & 15) * 4, tn = (t >> 4) * 4;
  float acc[4][4] = {};
  for (int k0 = 0; k0 < Ki; k0 += 16) {
    {
      const int row = t >> 2, q = t & 3;
      const float4 a4 = *(const float4*)(Am + (size_t)(m0 + row) * Ki + k0 + q * 4);
      As[q * 4 + 0][row] = a4.x; As[q * 4 + 1][row] = a4.y;
      As[q * 4 + 2][row] = a4.z; As[q * 4 + 3][row] = a4.w;
      const int kk = t >> 4, n4 = t & 15;
      *(float4*)&Bs[kk][n4 * 4] =
          *(const float4*)(Bm + (size_t)(k0 + kk) * Ni + n0 + n4 * 4);
    }
    __syncthreads();
#pragma unroll
    for (int kk = 0; kk < 16; ++kk) {
      const float4 av = *(const float4*)&As[kk][tm];
      const float4 bv = *(const float4*)&Bs[kk][tn];
      const float aa[4] = {av.x, av.y, av.z, av.w};
      const float bb[4] = {bv.x, bv.y, bv.z, bv.w};
#pragma unroll
      for (int i = 0; i < 4; ++i)
#pragma unroll
        for (int j = 0; j < 4; ++j) acc[i][j] += aa[i] * bb[j];
    }
    __syncthreads();
  }
#pragma unroll
  for (int i = 0; i < 4; ++i) {
    const int m = m0 + tm + i;
#pragma unroll
    for (int j = 0; j < 4; ++j) {
      const int n = n0 + tn + j;
      float v = acc[i][j];
      if (bias) v += bias[n];
      if (addm) v += addm[(size_t)m * Ni + n];
      Cm[(size_t)m * Ni + n] = v;
    }
  }
}

// ---------------- stage 1: bitwise-np f32 dists + stable top-32 ----------------
// dist_f32 = fsub(cb_sq, fmul(2, seqFMA(xt . cbrq))); key=(ordu,idx) ascending.
__global__ __launch_bounds__(512, 2) void k_stage1(
    const float* __restrict__ xt, const float* __restrict__ cbT,
    const float* __restrict__ cb_sq, int* __restrict__ topc) {
  __shared__ u32 distL[4 * 4096];  // 64 KB
  __shared__ float xtL[512];
  const int r0 = blockIdx.x * 4;
  const int t = threadIdx.x;
  xtL[t] = xt[r0 * 128 + t];  // 4 rows x 128
  __syncthreads();
  for (int kb = 0; kb < 8; ++kb) {
    const int k = kb * 512 + t;
    float a0 = 0.f, a1 = 0.f, a2 = 0.f, a3 = 0.f;
    for (int d = 0; d < 128; ++d) {
      const float cv = cbT[d * 4096 + k];
      a0 = __builtin_fmaf(xtL[d], cv, a0);
      a1 = __builtin_fmaf(xtL[128 + d], cv, a1);
      a2 = __builtin_fmaf(xtL[256 + d], cv, a2);
      a3 = __builtin_fmaf(xtL[384 + d], cv, a3);
    }
    const float cs = cb_sq[k];
    distL[k] = ordu(__fsub_rn(cs, __fmul_rn(2.0f, a0)));
    distL[4096 + k] = ordu(__fsub_rn(cs, __fmul_rn(2.0f, a1)));
    distL[8192 + k] = ordu(__fsub_rn(cs, __fmul_rn(2.0f, a2)));
    distL[12288 + k] = ordu(__fsub_rn(cs, __fmul_rn(2.0f, a3)));
  }
  __syncthreads();
  const int w = t >> 6, lane = t & 63;
  if (w < 4) {
    u32* dr = distL + w * 4096;
    for (int it = 0; it < 32; ++it) {
      u64 m = ~0ull;
      for (int e = 0; e < 64; ++e) {
        const int idx = e * 64 + lane;
        const u64 key = ((u64)dr[idx] << 32) | (u32)idx;
        m = (key < m) ? key : m;
      }
#pragma unroll
      for (int sh = 1; sh < 64; sh <<= 1) {
        const u64 o = __shfl_xor(m, sh);
        m = (o < m) ? o : m;
      }
      const int bi = (int)(m & 0xFFFFFFFFu);
      if (lane == 0) topc[(r0 + w) * 32 + it] = bi;
      if ((bi & 63) == lane) dr[bi] = 0xFFFFFFFFu;  // owner lane re-reads next it
    }
  }
}

// ---------------- stage 2: factored f32 MLP (PRESCREEN ONLY) ----------------
__global__ __launch_bounds__(256, 1) void k_mlp(
    const int* __restrict__ topc, const float* __restrict__ A1,
    const float* __restrict__ A2, const float* __restrict__ Dc,
    const float* __restrict__ B1, const float* __restrict__ B2,
    const float* __restrict__ Dr, const float* __restrict__ W21,
    const float* __restrict__ V1, const float* __restrict__ V2,
    const float* __restrict__ xhat, const float* __restrict__ x,
    float* __restrict__ d2g) {
  __shared__ float r1t[256 * 36];
  __shared__ float r2t[256 * 36];
  __shared__ float wst[16384];
  __shared__ float B1r[256], B2r[256], DrL[128], xhL[128], xL[128];
  __shared__ int codesL[32];
  __shared__ float d2red[32][33];

  const int r = blockIdx.x;
  const int bb = r >> 4;
  const int t = threadIdx.x;

  B1r[t] = B1[r * 256 + t];
  B2r[t] = B2[r * 256 + t];
  if (t < 128) {
    DrL[t] = Dr[r * 128 + t];
    xhL[t] = xhat[r * 128 + t];
    xL[t] = x[bb * 128 + t];
  }
  if (t < 32) codesL[t] = topc[r * 32 + t];
  __syncthreads();

  {
    const int c = t & 31, g = t >> 5;
    const int code = codesL[c];
    const float4* A14 = (const float4*)(A1 + code * 256 + g * 32);
#pragma unroll
    for (int e4 = 0; e4 < 8; ++e4) {
      const float4 a = A14[e4];
      const int i = g * 32 + e4 * 4;
      r1t[(i + 0) * 36 + c] = fmaxf(a.x + B1r[i + 0], 0.f);
      r1t[(i + 1) * 36 + c] = fmaxf(a.y + B1r[i + 1], 0.f);
      r1t[(i + 2) * 36 + c] = fmaxf(a.z + B1r[i + 2], 0.f);
      r1t[(i + 3) * 36 + c] = fmaxf(a.w + B1r[i + 3], 0.f);
    }
  }
  __syncthreads();

  const int c0 = (t & 7) * 4;
  const int j0 = (t >> 3) * 8;
  const float4* W214 = (const float4*)W21;
  const float4* V14 = (const float4*)V1;
  const float4* V24 = (const float4*)V2;
  float4* wst4 = (float4*)wst;
  const float4* r1t4 = (const float4*)r1t;
  const float4* r2t4 = (const float4*)r2t;

  float acc[4][8] = {};
  for (int ic = 0; ic < 4; ++ic) {
#pragma unroll
    for (int q = 0; q < 16; ++q)
      wst4[t + 256 * q] = W214[ic * 4096 + t + 256 * q];
    __syncthreads();
    for (int ii = 0; ii < 64; ++ii) {
      const int i = ic * 64 + ii;
      const float4 rv = r1t4[i * 9 + (c0 >> 2)];
      const float4 w0 = wst4[ii * 64 + (j0 >> 2)];
      const float4 w1 = wst4[ii * 64 + (j0 >> 2) + 1];
      const float ra[4] = {rv.x, rv.y, rv.z, rv.w};
      const float wa[8] = {w0.x, w0.y, w0.z, w0.w, w1.x, w1.y, w1.z, w1.w};
#pragma unroll
      for (int cc = 0; cc < 4; ++cc)
#pragma unroll
        for (int jj = 0; jj < 8; ++jj) acc[cc][jj] += ra[cc] * wa[jj];
    }
    __syncthreads();
  }
#pragma unroll
  for (int cc = 0; cc < 4; ++cc) {
    const int code = codesL[c0 + cc];
    const float4 a20 = *(const float4*)(A2 + code * 256 + j0);
    const float4 a21 = *(const float4*)(A2 + code * 256 + j0 + 4);
    const float a2v[8] = {a20.x, a20.y, a20.z, a20.w, a21.x, a21.y, a21.z, a21.w};
#pragma unroll
    for (int jj = 0; jj < 8; ++jj)
      acc[cc][jj] = fmaxf(acc[cc][jj] + a2v[jj] + B2r[j0 + jj], 0.f);
  }
#pragma unroll
  for (int jj = 0; jj < 8; ++jj) {
    float4 v;
    v.x = acc[0][jj]; v.y = acc[1][jj]; v.z = acc[2][jj]; v.w = acc[3][jj];
    *(float4*)&r2t[(j0 + jj) * 36 + c0] = v;
  }
  __syncthreads();

  const int d0 = (t >> 3) * 4;
  float acc2[4][4] = {};
  for (int ic = 0; ic < 4; ++ic) {
#pragma unroll
    for (int q = 0; q < 8; ++q) {
      wst4[t + 256 * q] = V14[ic * 2048 + t + 256 * q];
      wst4[2048 + t + 256 * q] = V24[ic * 2048 + t + 256 * q];
    }
    __syncthreads();
    for (int ii = 0; ii < 64; ++ii) {
      const int i = ic * 64 + ii;
      const float4 r1v = r1t4[i * 9 + (c0 >> 2)];
      const float4 r2v = r2t4[i * 9 + (c0 >> 2)];
      const float4 v1 = wst4[ii * 32 + (d0 >> 2)];
      const float4 v2 = wst4[2048 + ii * 32 + (d0 >> 2)];
      const float r1a[4] = {r1v.x, r1v.y, r1v.z, r1v.w};
      const float r2a[4] = {r2v.x, r2v.y, r2v.z, r2v.w};
      const float v1a[4] = {v1.x, v1.y, v1.z, v1.w};
      const float v2a[4] = {v2.x, v2.y, v2.z, v2.w};
#pragma unroll
      for (int cc = 0; cc < 4; ++cc)
#pragma unroll
        for (int dd = 0; dd < 4; ++dd)
          acc2[cc][dd] += r1a[cc] * v1a[dd] + r2a[cc] * v2a[dd];
    }
    __syncthreads();
  }
#pragma unroll
  for (int cc = 0; cc < 4; ++cc) {
    const int code = codesL[c0 + cc];
    const float4 dc = *(const float4*)(Dc + code * 128 + d0);
    const float dcv[4] = {dc.x, dc.y, dc.z, dc.w};
    float s = 0.f;
#pragma unroll
    for (int dd = 0; dd < 4; ++dd) {
      const int d = d0 + dd;
      const float cand = acc2[cc][dd] + dcv[dd] + DrL[d] + xhL[d];
      s += cand * cand - 2.f * xL[d] * cand;
    }
    d2red[c0 + cc][t >> 3] = s;
  }
  __syncthreads();
  if (t < 32) {
    float s = 0.f;
#pragma unroll
    for (int g = 0; g < 32; ++g) s += d2red[t][g];
    d2g[bb * 512 + (r & 15) * 32 + t] = s;
  }
}

// ---------------- stage 3a: prescreen top-32 per base query ----------------
__global__ __launch_bounds__(64, 1) void k_sel32(const float* __restrict__ d2g,
                                                 int* __restrict__ sel32) {
  __shared__ u32 d2u[512];
  const int bb = blockIdx.x;
  const int t = threadIdx.x;
  for (int i = t; i < 512; i += 64) d2u[i] = ordu(d2g[bb * 512 + i]);
  __syncthreads();
  for (int it = 0; it < 32; ++it) {
    u64 m = ~0ull;
#pragma unroll
    for (int e = 0; e < 8; ++e) {
      const int idx = e * 64 + t;
      const u64 key = ((u64)d2u[idx] << 32) | (u32)idx;
      m = (key < m) ? key : m;
    }
#pragma unroll
    for (int sh = 1; sh < 64; sh <<= 1) {
      const u64 o = __shfl_xor(m, sh);
      m = (o < m) ? o : m;
    }
    const int s = (int)(m & 0xFFFFFFFFu);
    if ((s & 63) == t) d2u[s] = 0xFFFFFFFFu;
    if (t == 0) sel32[bb * 32 + it] = s;
  }
}

// ---------------- stage 3b: np-emulated rescore of top-32 ----------------
// 8 candidates/block (4 blocks/query). seq-FMA matmuls; s1 via exact numpy
// pairwise-8; s2 correctly rounded; d2 = f32 fsub(s1, fmul(2, s2)).
__global__ __launch_bounds__(256, 2) void k_rescore(
    const int* __restrict__ sel32, const int* __restrict__ topc,
    const float* __restrict__ tmp_h, const float* __restrict__ cb,
    const float* __restrict__ xhat, const float* __restrict__ x,
    const float* __restrict__ cc_w, const float* __restrict__ cc_b,
    const float* __restrict__ rb_w1, const float* __restrict__ rb_b1,
    const float* __restrict__ rb_w2, const float* __restrict__ rb_b2,
    const float* __restrict__ out_w, const float* __restrict__ out_b,
    float* __restrict__ d2r, float* __restrict__ candv) {
  __shared__ float A_[8][256], B_[8][256], C_[8][256];
  __shared__ float cbL[8][128], xhL[8][128], candL[8][128], xqL[128];
  __shared__ int codeL[8], rowL[8];
  const int bb = blockIdx.x >> 2;
  const int j0 = (blockIdx.x & 3) * 8;
  const int t = threadIdx.x;
  if (t < 8) {
    const int s = sel32[bb * 32 + j0 + t];
    rowL[t] = bb * 16 + (s >> 5);
    codeL[t] = topc[(bb * 16 + (s >> 5)) * 32 + (s & 31)];
  }
  if (t < 128) xqL[t] = x[bb * 128 + t];
  __syncthreads();
  for (int idx = t; idx < 1024; idx += 256) {
    const int c = idx >> 7, d = idx & 127;
    cbL[c][d] = cb[codeL[c] * 128 + d];
    xhL[c][d] = xhat[rowL[c] * 128 + d];
  }
  for (int idx = t; idx < 2048; idx += 256) {
    const int c = idx >> 8, i = idx & 255;
    A_[c][i] = tmp_h[codeL[c] * 256 + i];  // h_in (np-identical)
  }
  __syncthreads();
  // h0 = seqFMA(concat(h_in, xhat) @ cc_w) + cc_b  -> B_
  {
    float acc[8] = {};
    for (int i = 0; i < 256; ++i) {
      const float w = cc_w[i * 256 + t];
#pragma unroll
      for (int c = 0; c < 8; ++c) acc[c] = __builtin_fmaf(A_[c][i], w, acc[c]);
    }
    for (int d = 0; d < 128; ++d) {
      const float w = cc_w[(256 + d) * 256 + t];
#pragma unroll
      for (int c = 0; c < 8; ++c) acc[c] = __builtin_fmaf(xhL[c][d], w, acc[c]);
    }
    const float b = cc_b[t];
#pragma unroll
    for (int c = 0; c < 8; ++c) B_[c][t] = __fadd_rn(acc[c], b);
  }
  __syncthreads();
  // r1 = relu(seqFMA(h0 @ w1_0) + b1_0) -> C_
  {
    float acc[8] = {};
    for (int i = 0; i < 256; ++i) {
      const float w = rb_w1[i * 256 + t];
#pragma unroll
      for (int c = 0; c < 8; ++c) acc[c] = __builtin_fmaf(B_[c][i], w, acc[c]);
    }
    const float b = rb_b1[t];
#pragma unroll
    for (int c = 0; c < 8; ++c) C_[c][t] = fmaxf(__fadd_rn(acc[c], b), 0.f);
  }
  __syncthreads();
  // h1 = (h0 + seqFMA(r1 @ w2_0)) + b2_0 -> A_
  {
    float acc[8] = {};
    for (int i = 0; i < 256; ++i) {
      const float w = rb_w2[i * 256 + t];
#pragma unroll
      for (int c = 0; c < 8; ++c) acc[c] = __builtin_fmaf(C_[c][i], w, acc[c]);
    }
    const float b = rb_b2[t];
#pragma unroll
    for (int c = 0; c < 8; ++c)
      A_[c][t] = __fadd_rn(__fadd_rn(B_[c][t], acc[c]), b);
  }
  __syncthreads();
  // r2 = relu(seqFMA(h1 @ w1_1) + b1_1) -> B_
  {
    float acc[8] = {};
    const float* w11 = rb_w1 + 65536;
    for (int i = 0; i < 256; ++i) {
      const float w = w11[i * 256 + t];
#pragma unroll
      for (int c = 0; c < 8; ++c) acc[c] = __builtin_fmaf(A_[c][i], w, acc[c]);
    }
    const float b = rb_b1[256 + t];
#pragma unroll
    for (int c = 0; c < 8; ++c) B_[c][t] = fmaxf(__fadd_rn(acc[c], b), 0.f);
  }
  __syncthreads();
  // h2 = (h1 + seqFMA(r2 @ w2_1)) + b2_1 -> C_
  {
    float acc[8] = {};
    const float* w21 = rb_w2 + 65536;
    for (int i = 0; i < 256; ++i) {
      const float w = w21[i * 256 + t];
#pragma unroll
      for (int c = 0; c < 8; ++c) acc[c] = __builtin_fmaf(B_[c][i], w, acc[c]);
    }
    const float b = rb_b2[256 + t];
#pragma unroll
    for (int c = 0; c < 8; ++c)
      C_[c][t] = __fadd_rn(__fadd_rn(A_[c][t], acc[c]), b);
  }
  __syncthreads();
  // cand = ((seqFMA(h2@out_w) + out_b) + cw_in) + xhat
  if (t < 128) {
    float acc[8] = {};
    for (int i = 0; i < 256; ++i) {
      const float w = out_w[i * 128 + t];
#pragma unroll
      for (int c = 0; c < 8; ++c) acc[c] = __builtin_fmaf(C_[c][i], w, acc[c]);
    }
    const float ob = out_b[t];
#pragma unroll
    for (int c = 0; c < 8; ++c) {
      const float cw_ = __fadd_rn(__fadd_rn(acc[c], ob), cbL[c][t]);
      const float cand = __fadd_rn(cw_, xhL[c][t]);
      candL[c][t] = cand;
      candv[(bb * 32 + j0 + c) * 128 + t] = cand;
    }
  }
  __syncthreads();
  // s1 = np.sum pairwise-8 of cand^2 (exact); s2 = einsum ~ correctly rounded;
  // d2 = fsub(s1, fmul(2, s2)) in f32  (NEP50: all-f32 chain)
  if (t < 8) {
    float r[8];
#pragma unroll
    for (int j = 0; j < 8; ++j) {
      const float v = candL[t][j];
      r[j] = __fmul_rn(v, v);
    }
    for (int i = 8; i < 128; i += 8) {
#pragma unroll
      for (int j = 0; j < 8; ++j) {
        const float v = candL[t][i + j];
        r[j] = __fadd_rn(r[j], __fmul_rn(v, v));
      }
    }
    const float s1f = __fadd_rn(
        __fadd_rn(__fadd_rn(r[0], r[1]), __fadd_rn(r[2], r[3])),
        __fadd_rn(__fadd_rn(r[4], r[5]), __fadd_rn(r[6], r[7])));
    double s2 = 0.0;
    for (int d = 0; d < 128; ++d)
      s2 += (double)xqL[d] * (double)candL[t][d];
    const float s2f = (float)s2;
    d2r[bb * 32 + j0 + t] = __fsub_rn(s1f, __fmul_rn(2.0f, s2f));
  }
}

// ---------------- stage 3c/4: stable top-16 by f32 d2 (tie -> lower flat idx) ----------------
__global__ __launch_bounds__(64, 1) void k_final(
    const float* __restrict__ d2r, const int* __restrict__ sel32,
    const int* __restrict__ topc, const int* __restrict__ codes_in,
    const float* __restrict__ candv, float* __restrict__ out) {
  __shared__ u32 winLo[16];
  const int bb = blockIdx.x;
  const int t = threadIdx.x;  // 64
  u64 key = ~0ull;
  if (t < 32) {
    const u32 s = (u32)sel32[bb * 32 + t];  // flat candidate idx in [0,512)
    key = ((u64)ordu(d2r[bb * 32 + t]) << 32) | (s << 5) | (u32)t;
  }
  for (int it = 0; it < 16; ++it) {
    u64 m = key;
#pragma unroll
    for (int sh = 1; sh < 64; sh <<= 1) {
      const u64 o = __shfl_xor(m, sh);
      m = (o < m) ? o : m;
    }
    if (key == m) key = ~0ull;  // unique low bits -> only winner clears
    if (t == 0) winLo[it] = (u32)(m & 0xFFFFFFFFu);
  }
  __syncthreads();
  if (t < 16) {
    const u32 lo = winLo[t];
    const int s = (int)((lo >> 5) & 511u);
    const int f = s >> 5;
    const int code = topc[(bb * 16 + f) * 32 + (s & 31)];
    float* oc = out + 512 * 16 * 128;  // codes [3][512][16]
    oc[bb * 16 + t] = (float)codes_in[bb * 16 + f];
    oc[8192 + bb * 16 + t] = (float)codes_in[8192 + bb * 16 + f];
    oc[16384 + bb * 16 + t] = (float)code;
  }
  __syncthreads();
  for (int idx = t; idx < 2048; idx += 64) {
    const int w_ = idx >> 7, d = idx & 127;
    const int j = (int)(winLo[w_] & 31u);
    out[(bb * 16 + w_) * 128 + d] = candv[(bb * 32 + j) * 128 + d];
  }
}

// ---------------- launch ----------------
extern "C" void kernel_launch(void* const* d_in, const int* in_sizes, int n_in,
                              void* d_out, int out_size, void* d_ws,
                              size_t ws_size, hipStream_t stream) {
  const float* x = (const float*)d_in[0];
  const float* xhat = (const float*)d_in[1];
  const int* codes = (const int*)d_in[2];
  const float* cb = (const float*)d_in[3];
  const float* cbrq = (const float*)d_in[4];
  const float* in_w = (const float*)d_in[5];
  const float* in_b = (const float*)d_in[6];
  const float* cc_w = (const float*)d_in[7];
  const float* cc_b = (const float*)d_in[8];
  const float* rb_w1 = (const float*)d_in[9];
  const float* rb_b1 = (const float*)d_in[10];
  const float* rb_w2 = (const float*)d_in[11];
  const float* rb_b2 = (const float*)d_in[12];
  const float* out_w = (const float*)d_in[13];
  const float* out_b = (const float*)d_in[14];
  float* out = (float*)d_out;

  float* ws = (float*)d_ws;
  size_t o = 0;
  float* cb_sq = ws + o; o += 4096;
  float* xt = ws + o;    const size_t xt_off = o; o += (size_t)8192 * 128;
  float* cbT = ws + o;   o += (size_t)128 * 4096;
  float* tmp_h = ws + o; o += (size_t)4096 * 256;   // LIVE through k_rescore
  float* pc = ws + o;    const size_t pc_off = o; o += (size_t)4096 * 256;
  float* pb = ws + o;    o += (size_t)8192 * 256;
  float* A1 = ws + o;    o += (size_t)4096 * 256;
  float* A2 = ws + o;    o += (size_t)4096 * 256;
  float* Dc = ws + o;    o += (size_t)4096 * 128;
  float* B1 = ws + o;    o += (size_t)8192 * 256;
  float* B2 = ws + o;    o += (size_t)8192 * 256;
  float* Dr = ws + o;    o += (size_t)8192 * 128;
  float* W21 = ws + o;   o += 65536;
  float* V1 = ws + o;    o += 32768;
  float* V2 = ws + o;    o += 32768;
  float* bias2v = ws + o; o += 256;
  float* biasDv = ws + o; o += 128;
  int* topc = (int*)(ws + o); o += 262144;
  float* d2g = ws + o;   o += 262144;
  // aliases into dead regions:
  float* d2r = ws + xt_off;                   // 16384 floats (xt dead post-stage1)
  int* sel32 = (int*)(ws + xt_off + 16384);   // 16384 ints
  float* candv = ws + pc_off;                 // 16384*128 floats (pc/pb dead)

  k_cbrqT<<<dim3(128), dim3(256), 0, stream>>>(cbrq, cbT);
  k_cbsq<<<dim3(16), dim3(256), 0, stream>>>(cbT, cb_sq);
  k_xt<<<dim3(1024), dim3(256), 0, stream>>>(x, xhat, xt);
  k_biasprep<<<dim3(1), dim3(256), 0, stream>>>(rb_b1, rb_b2, rb_w1, out_w,
                                                out_b, bias2v, biasDv);
  k_codeh<<<dim3(4096), dim3(256), 0, stream>>>(cb, in_w, in_b, tmp_h);
  gemm_f32<<<dim3(64, 4), dim3(256), 0, stream>>>(tmp_h, cc_w, pc, 4096, 256,
                                                  256, nullptr, nullptr);
  gemm_f32<<<dim3(128, 4), dim3(256), 0, stream>>>(xhat, cc_w + 256 * 256, pb,
                                                   8192, 256, 128, cc_b,
                                                   nullptr);
  gemm_f32<<<dim3(64, 4), dim3(256), 0, stream>>>(pc, rb_w1, A1, 4096, 256, 256,
                                                  nullptr, nullptr);
  gemm_f32<<<dim3(64, 4), dim3(256), 0, stream>>>(pc, rb_w1 + 65536, A2, 4096,
                                                  256, 256, nullptr, nullptr);
  gemm_f32<<<dim3(64, 2), dim3(256), 0, stream>>>(pc, out_w, Dc, 4096, 128, 256,
                                                  nullptr, cb);
  gemm_f32<<<dim3(128, 4), dim3(256), 0, stream>>>(pb, rb_w1, B1, 8192, 256,
                                                   256, rb_b1, nullptr);
  gemm_f32<<<dim3(128, 4), dim3(256), 0, stream>>>(pb, rb_w1 + 65536, B2, 8192,
                                                   256, 256, bias2v, nullptr);
  gemm_f32<<<dim3(128, 2), dim3(256), 0, stream>>>(pb, out_w, Dr, 8192, 128,
                                                   256, biasDv, nullptr);
  gemm_f32<<<dim3(4, 4), dim3(256), 0, stream>>>(rb_w2, rb_w1 + 65536, W21, 256,
                                                 256, 256, nullptr, nullptr);
  gemm_f32<<<dim3(4, 2), dim3(256), 0, stream>>>(rb_w2, out_w, V1, 256, 128,
                                                 256, nullptr, nullptr);
  gemm_f32<<<dim3(4, 2), dim3(256), 0, stream>>>(rb_w2 + 65536, out_w, V2, 256,
                                                 128, 256, nullptr, nullptr);

  k_stage1<<<dim3(2048), dim3(512), 0, stream>>>(xt, cbT, cb_sq, topc);
  k_mlp<<<dim3(8192), dim3(256), 0, stream>>>(topc, A1, A2, Dc, B1, B2, Dr, W21,
                                              V1, V2, xhat, x, d2g);
  k_sel32<<<dim3(512), dim3(64), 0, stream>>>(d2g, sel32);
  k_rescore<<<dim3(2048), dim3(256), 0, stream>>>(
      sel32, topc, tmp_h, cb, xhat, x, cc_w, cc_b, rb_w1, rb_b1, rb_w2, rb_b2,
      out_w, out_b, d2r, candv);
  k_final<<<dim3(512), dim3(64), 0, stream>>>(d2r, sel32, topc, codes, candv,
                                              out);
  (void)in_sizes; (void)n_in; (void)out_size; (void)ws_size;
}

// Round 8
// 1973.848 us; speedup vs baseline: 1.2585x; 1.2585x over previous
//
#include <hip/hip_runtime.h>
#include <float.h>

typedef unsigned int u32;
typedef unsigned long long u64;

// Bb=512, F=16 -> 8192 beam rows, D=128, DH=256, K=4096, A=32, Fo=16, M=2.
// Selection-critical math reproduces numpy's f32 arithmetic bitwise (model):
//  - matmul: per-output sequential f32 FMA over k ascending (sgemm micro-kernel)
//  - np.sum(last axis): 8-accumulator pairwise (n<=128 base case), no FMA
//  - dist/d2 combine: separate f32 mul + f32 sub (ufuncs don't fuse)
//  - all top-k: f32 keys, ties -> lower index (stable, = jax top_k & np)
// The factored-f32 MLP is a prescreen only (top-32 cut, huge margin).

static __device__ __forceinline__ u32 ordu(float f) {
  u32 u = __float_as_uint(f);
  return u ^ (u32)(((int)u >> 31) | (int)0x80000000);
}

// ---------------- prep ----------------

// codebook_rq [4096][128] -> cbT [128][4096]
__global__ __launch_bounds__(256) void k_cbrqT(const float* __restrict__ cbrq,
                                               float* __restrict__ cbT) {
  __shared__ float tile[128 * 33];
  const int k0 = blockIdx.x * 32;
  const int t = threadIdx.x;
#pragma unroll
  for (int rep = 0; rep < 16; ++rep) {
    const int flat = rep * 256 + t;
    const int kk = flat >> 7, d = flat & 127;
    tile[d * 33 + kk] = cbrq[(k0 + kk) * 128 + d];
  }
  __syncthreads();
#pragma unroll
  for (int rep = 0; rep < 16; ++rep) {
    const int flat = rep * 256 + t;
    const int d = flat >> 5, kk = flat & 31;
    cbT[d * 4096 + k0 + kk] = tile[d * 33 + kk];
  }
}

// cb_sq[k] = np.sum pairwise-8 emulation (exact), via cbT for coalescing
__global__ __launch_bounds__(256) void k_cbsq(const float* __restrict__ cbT,
                                              float* __restrict__ cb_sq) {
  const int k = blockIdx.x * 256 + threadIdx.x;
  float r[8];
#pragma unroll
  for (int j = 0; j < 8; ++j) {
    const float v = cbT[j * 4096 + k];
    r[j] = __fmul_rn(v, v);
  }
  for (int i = 8; i < 128; i += 8) {
#pragma unroll
    for (int j = 0; j < 8; ++j) {
      const float v = cbT[(i + j) * 4096 + k];
      r[j] = __fadd_rn(r[j], __fmul_rn(v, v));
    }
  }
  cb_sq[k] = __fadd_rn(
      __fadd_rn(__fadd_rn(r[0], r[1]), __fadd_rn(r[2], r[3])),
      __fadd_rn(__fadd_rn(r[4], r[5]), __fadd_rn(r[6], r[7])));
}

// xt f32 = x - xhat
__global__ __launch_bounds__(256) void k_xt(const float* __restrict__ x,
                                            const float* __restrict__ xhat,
                                            float* __restrict__ xt) {
  const int i = blockIdx.x * 256 + threadIdx.x;
  const int row = i >> 5, d4 = i & 31;
  const float4 a = ((const float4*)x)[(row >> 4) * 32 + d4];
  const float4 b = ((const float4*)xhat)[i];
  float4 r;
  r.x = __fsub_rn(a.x, b.x); r.y = __fsub_rn(a.y, b.y);
  r.z = __fsub_rn(a.z, b.z); r.w = __fsub_rn(a.w, b.w);
  ((float4*)xt)[i] = r;
}

// tmp_h[code][j] = seqFMA_d(cb[code][d]*in_w[d][j]) + in_b[j]
__global__ __launch_bounds__(256) void k_codeh(const float* __restrict__ cb,
                                               const float* __restrict__ in_w,
                                               const float* __restrict__ in_b,
                                               float* __restrict__ tmp_h) {
  __shared__ float row[128];
  const int code = blockIdx.x;
  const int t = threadIdx.x;
  if (t < 128) row[t] = cb[code * 128 + t];
  __syncthreads();
  float a = 0.f;
  for (int d = 0; d < 128; ++d) a = __builtin_fmaf(row[d], in_w[d * 256 + t], a);
  tmp_h[code * 256 + t] = __fadd_rn(a, in_b[t]);
}

// prescreen bias prep
__global__ __launch_bounds__(256) void k_biasprep(
    const float* __restrict__ rb_b1, const float* __restrict__ rb_b2,
    const float* __restrict__ rb_w1, const float* __restrict__ out_w,
    const float* __restrict__ out_b, float* __restrict__ bias2v,
    float* __restrict__ biasDv) {
  const int t = threadIdx.x;
  const float* w11 = rb_w1 + 65536;
  float s = rb_b1[256 + t];
  for (int i = 0; i < 256; ++i) s += rb_b2[i] * w11[i * 256 + t];
  bias2v[t] = s;
  if (t < 128) {
    float s2 = out_b[t];
    for (int i = 0; i < 256; ++i)
      s2 += (rb_b2[i] + rb_b2[256 + i]) * out_w[i * 128 + t];
    biasDv[t] = s2;
  }
}

// ---------------- generic f32 GEMM (prescreen precompute only) ----------------
__global__ __launch_bounds__(256, 4) void gemm_f32(
    const float* __restrict__ Am, const float* __restrict__ Bm,
    float* __restrict__ Cm, const int Mi, const int Ni, const int Ki,
    const float* __restrict__ bias, const float* __restrict__ addm) {
  __shared__ float As[16][68];
  __shared__ float Bs[16][68];
  const int m0 = blockIdx.x * 64, n0 = blockIdx.y * 64;
  const int t = threadIdx.x;
  const int tm = (t & 15) * 4, tn = (t >> 4) * 4;
  float acc[4][4] = {};
  for (int k0 = 0; k0 < Ki; k0 += 16) {
    {
      const int row = t >> 2, q = t & 3;
      const float4 a4 = *(const float4*)(Am + (size_t)(m0 + row) * Ki + k0 + q * 4);
      As[q * 4 + 0][row] = a4.x; As[q * 4 + 1][row] = a4.y;
      As[q * 4 + 2][row] = a4.z; As[q * 4 + 3][row] = a4.w;
      const int kk = t >> 4, n4 = t & 15;
      *(float4*)&Bs[kk][n4 * 4] =
          *(const float4*)(Bm + (size_t)(k0 + kk) * Ni + n0 + n4 * 4);
    }
    __syncthreads();
#pragma unroll
    for (int kk = 0; kk < 16; ++kk) {
      const float4 av = *(const float4*)&As[kk][tm];
      const float4 bv = *(const float4*)&Bs[kk][tn];
      const float aa[4] = {av.x, av.y, av.z, av.w};
      const float bb[4] = {bv.x, bv.y, bv.z, bv.w};
#pragma unroll
      for (int i = 0; i < 4; ++i)
#pragma unroll
        for (int j = 0; j < 4; ++j) acc[i][j] += aa[i] * bb[j];
    }
    __syncthreads();
  }
#pragma unroll
  for (int i = 0; i < 4; ++i) {
    const int m = m0 + tm + i;
#pragma unroll
    for (int j = 0; j < 4; ++j) {
      const int n = n0 + tn + j;
      float v = acc[i][j];
      if (bias) v += bias[n];
      if (addm) v += addm[(size_t)m * Ni + n];
      Cm[(size_t)m * Ni + n] = v;
    }
  }
}

// ---------------- stage 1: bitwise-np f32 dists + stable top-32 ----------------
__global__ __launch_bounds__(512, 2) void k_stage1(
    const float* __restrict__ xt, const float* __restrict__ cbT,
    const float* __restrict__ cb_sq, int* __restrict__ topc) {
  __shared__ u32 distL[4 * 4096];  // 64 KB
  __shared__ float xtL[512];
  const int r0 = blockIdx.x * 4;
  const int t = threadIdx.x;
  xtL[t] = xt[r0 * 128 + t];
  __syncthreads();
  for (int kb = 0; kb < 8; ++kb) {
    const int k = kb * 512 + t;
    float a0 = 0.f, a1 = 0.f, a2 = 0.f, a3 = 0.f;
    for (int d = 0; d < 128; ++d) {
      const float cv = cbT[d * 4096 + k];
      a0 = __builtin_fmaf(xtL[d], cv, a0);
      a1 = __builtin_fmaf(xtL[128 + d], cv, a1);
      a2 = __builtin_fmaf(xtL[256 + d], cv, a2);
      a3 = __builtin_fmaf(xtL[384 + d], cv, a3);
    }
    const float cs = cb_sq[k];
    distL[k] = ordu(__fsub_rn(cs, __fmul_rn(2.0f, a0)));
    distL[4096 + k] = ordu(__fsub_rn(cs, __fmul_rn(2.0f, a1)));
    distL[8192 + k] = ordu(__fsub_rn(cs, __fmul_rn(2.0f, a2)));
    distL[12288 + k] = ordu(__fsub_rn(cs, __fmul_rn(2.0f, a3)));
  }
  __syncthreads();
  const int w = t >> 6, lane = t & 63;
  if (w < 4) {
    u32* dr = distL + w * 4096;
    for (int it = 0; it < 32; ++it) {
      u64 m = ~0ull;
      for (int e = 0; e < 64; ++e) {
        const int idx = e * 64 + lane;
        const u64 key = ((u64)dr[idx] << 32) | (u32)idx;
        m = (key < m) ? key : m;
      }
#pragma unroll
      for (int sh = 1; sh < 64; sh <<= 1) {
        const u64 o = __shfl_xor(m, sh);
        m = (o < m) ? o : m;
      }
      const int bi = (int)(m & 0xFFFFFFFFu);
      if (lane == 0) topc[(r0 + w) * 32 + it] = bi;
      if ((bi & 63) == lane) dr[bi] = 0xFFFFFFFFu;
    }
  }
}

// ---------------- stage 2: factored f32 MLP prescreen ----------------
// 2 beam rows/block, 512 threads (row = t>>8). Weights (W21,V1,V2) read
// directly from L2; single 32KB/row activation buffer reused r1 -> r2.
// LDS ~74.5 KB -> 2 blocks/CU -> 4 waves/SIMD.
__global__ __launch_bounds__(512, 4) void k_mlp(
    const int* __restrict__ topc, const float* __restrict__ A1,
    const float* __restrict__ A2, const float* __restrict__ Dc,
    const float* __restrict__ B1, const float* __restrict__ B2,
    const float* __restrict__ Dr, const float* __restrict__ W21,
    const float* __restrict__ V1, const float* __restrict__ V2,
    const float* __restrict__ xhat, const float* __restrict__ x,
    float* __restrict__ d2g) {
  __shared__ float sbuf[2][256 * 32];  // [i][c] r1, later [j][c] r2
  __shared__ float B1r[2][256];
  __shared__ int codesL[2][32];
  __shared__ float d2red[2][32][33];

  const int t = threadIdx.x;
  const int row = t >> 8, tt = t & 255;
  const int r = blockIdx.x * 2 + row;  // beam row
  const int bb = r >> 4;

  B1r[row][tt] = B1[r * 256 + tt];
  if (tt < 32) codesL[row][tt] = topc[r * 32 + tt];
  __syncthreads();

  // phase 1: r1 = relu(A1[code] + B1[row]) -> sbuf [i][c]
  {
    const int c = tt & 31, g = tt >> 5;
    const int code = codesL[row][c];
    const float4* A14 = (const float4*)(A1 + code * 256 + g * 32);
    float* sb = sbuf[row];
#pragma unroll
    for (int e4 = 0; e4 < 8; ++e4) {
      const float4 a = A14[e4];
      const int i = g * 32 + e4 * 4;
      sb[(i + 0) * 32 + c] = fmaxf(a.x + B1r[row][i + 0], 0.f);
      sb[(i + 1) * 32 + c] = fmaxf(a.y + B1r[row][i + 1], 0.f);
      sb[(i + 2) * 32 + c] = fmaxf(a.z + B1r[row][i + 2], 0.f);
      sb[(i + 3) * 32 + c] = fmaxf(a.w + B1r[row][i + 3], 0.f);
    }
  }
  __syncthreads();

  const int c0 = (tt & 7) * 4;
  const float* sb = sbuf[row];
  const int d0 = (tt >> 3) * 4;
  const int j0 = (tt >> 3) * 8;

  // phase 3a: acc2 = r1 @ V1   (V1 from L2)
  float acc2[4][4] = {};
  for (int i = 0; i < 256; ++i) {
    const float4 rv = *(const float4*)&sb[i * 32 + c0];
    const float4 v1 = *(const float4*)&V1[i * 128 + d0];
    const float ra[4] = {rv.x, rv.y, rv.z, rv.w};
    const float va[4] = {v1.x, v1.y, v1.z, v1.w};
#pragma unroll
    for (int cc = 0; cc < 4; ++cc)
#pragma unroll
      for (int dd = 0; dd < 4; ++dd)
        acc2[cc][dd] += ra[cc] * va[dd];
  }

  // phase 2: z2 = r1 @ W21  (W21 from L2)
  float acc[4][8] = {};
  for (int i = 0; i < 256; ++i) {
    const float4 rv = *(const float4*)&sb[i * 32 + c0];
    const float4 w0 = *(const float4*)&W21[i * 256 + j0];
    const float4 w1 = *(const float4*)&W21[i * 256 + j0 + 4];
    const float ra[4] = {rv.x, rv.y, rv.z, rv.w};
    const float wa[8] = {w0.x, w0.y, w0.z, w0.w, w1.x, w1.y, w1.z, w1.w};
#pragma unroll
    for (int cc = 0; cc < 4; ++cc)
#pragma unroll
      for (int jj = 0; jj < 8; ++jj) acc[cc][jj] += ra[cc] * wa[jj];
  }
  // z2 += A2[code]+B2[row], relu
  {
    const float4 b20 = *(const float4*)&B2[r * 256 + j0];
    const float4 b21 = *(const float4*)&B2[r * 256 + j0 + 4];
    const float b2v[8] = {b20.x, b20.y, b20.z, b20.w,
                          b21.x, b21.y, b21.z, b21.w};
#pragma unroll
    for (int cc = 0; cc < 4; ++cc) {
      const int code = codesL[row][c0 + cc];
      const float4 a20 = *(const float4*)&A2[code * 256 + j0];
      const float4 a21 = *(const float4*)&A2[code * 256 + j0 + 4];
      const float a2v[8] = {a20.x, a20.y, a20.z, a20.w,
                            a21.x, a21.y, a21.z, a21.w};
#pragma unroll
      for (int jj = 0; jj < 8; ++jj)
        acc[cc][jj] = fmaxf(acc[cc][jj] + a2v[jj] + b2v[jj], 0.f);
    }
  }
  __syncthreads();  // all reads of r1 in sbuf complete
  // write r2 into sbuf [j][c]
  {
    float* sbw = sbuf[row];
#pragma unroll
    for (int jj = 0; jj < 8; ++jj) {
      float4 v;
      v.x = acc[0][jj]; v.y = acc[1][jj]; v.z = acc[2][jj]; v.w = acc[3][jj];
      *(float4*)&sbw[(j0 + jj) * 32 + c0] = v;
    }
  }
  __syncthreads();

  // phase 3b: acc2 += r2 @ V2  (V2 from L2)
  for (int j = 0; j < 256; ++j) {
    const float4 rv = *(const float4*)&sb[j * 32 + c0];
    const float4 v2 = *(const float4*)&V2[j * 128 + d0];
    const float ra[4] = {rv.x, rv.y, rv.z, rv.w};
    const float va[4] = {v2.x, v2.y, v2.z, v2.w};
#pragma unroll
    for (int cc = 0; cc < 4; ++cc)
#pragma unroll
      for (int dd = 0; dd < 4; ++dd)
        acc2[cc][dd] += ra[cc] * va[dd];
  }

  // epilogue: d2 partials (operands from L2)
  {
    const float4 drv = *(const float4*)&Dr[r * 128 + d0];
    const float4 xh = *(const float4*)&xhat[r * 128 + d0];
    const float4 xv = *(const float4*)&x[bb * 128 + d0];
    const float drL[4] = {drv.x, drv.y, drv.z, drv.w};
    const float xhL[4] = {xh.x, xh.y, xh.z, xh.w};
    const float xL[4] = {xv.x, xv.y, xv.z, xv.w};
#pragma unroll
    for (int cc = 0; cc < 4; ++cc) {
      const int code = codesL[row][c0 + cc];
      const float4 dc = *(const float4*)&Dc[code * 128 + d0];
      const float dcv[4] = {dc.x, dc.y, dc.z, dc.w};
      float s = 0.f;
#pragma unroll
      for (int dd = 0; dd < 4; ++dd) {
        const float cand = acc2[cc][dd] + dcv[dd] + drL[dd] + xhL[dd];
        s += cand * cand - 2.f * xL[dd] * cand;
      }
      d2red[row][c0 + cc][tt >> 3] = s;
    }
  }
  __syncthreads();
  if (tt < 32) {
    float s = 0.f;
#pragma unroll
    for (int g = 0; g < 32; ++g) s += d2red[row][tt][g];
    d2g[bb * 512 + (r & 15) * 32 + tt] = s;
  }
}

// ---------------- stage 3a: prescreen top-32 per base query ----------------
__global__ __launch_bounds__(64, 1) void k_sel32(const float* __restrict__ d2g,
                                                 int* __restrict__ sel32) {
  __shared__ u32 d2u[512];
  const int bb = blockIdx.x;
  const int t = threadIdx.x;
  for (int i = t; i < 512; i += 64) d2u[i] = ordu(d2g[bb * 512 + i]);
  __syncthreads();
  for (int it = 0; it < 32; ++it) {
    u64 m = ~0ull;
#pragma unroll
    for (int e = 0; e < 8; ++e) {
      const int idx = e * 64 + t;
      const u64 key = ((u64)d2u[idx] << 32) | (u32)idx;
      m = (key < m) ? key : m;
    }
#pragma unroll
    for (int sh = 1; sh < 64; sh <<= 1) {
      const u64 o = __shfl_xor(m, sh);
      m = (o < m) ? o : m;
    }
    const int s = (int)(m & 0xFFFFFFFFu);
    if ((s & 63) == t) d2u[s] = 0xFFFFFFFFu;
    if (t == 0) sel32[bb * 32 + it] = s;
  }
}

// ---------------- stage 3b: np-emulated rescore of top-32 ----------------
__global__ __launch_bounds__(256, 4) void k_rescore(
    const int* __restrict__ sel32, const int* __restrict__ topc,
    const float* __restrict__ tmp_h, const float* __restrict__ cb,
    const float* __restrict__ xhat, const float* __restrict__ x,
    const float* __restrict__ cc_w, const float* __restrict__ cc_b,
    const float* __restrict__ rb_w1, const float* __restrict__ rb_b1,
    const float* __restrict__ rb_w2, const float* __restrict__ rb_b2,
    const float* __restrict__ out_w, const float* __restrict__ out_b,
    float* __restrict__ d2r, float* __restrict__ candv) {
  __shared__ float A_[8][256], B_[8][256], C_[8][256];
  __shared__ float cbL[8][128], xhL[8][128], candL[8][128], xqL[128];
  __shared__ int codeL[8], rowL[8];
  const int bb = blockIdx.x >> 2;
  const int j0 = (blockIdx.x & 3) * 8;
  const int t = threadIdx.x;
  if (t < 8) {
    const int s = sel32[bb * 32 + j0 + t];
    rowL[t] = bb * 16 + (s >> 5);
    codeL[t] = topc[(bb * 16 + (s >> 5)) * 32 + (s & 31)];
  }
  if (t < 128) xqL[t] = x[bb * 128 + t];
  __syncthreads();
  for (int idx = t; idx < 1024; idx += 256) {
    const int c = idx >> 7, d = idx & 127;
    cbL[c][d] = cb[codeL[c] * 128 + d];
    xhL[c][d] = xhat[rowL[c] * 128 + d];
  }
  for (int idx = t; idx < 2048; idx += 256) {
    const int c = idx >> 8, i = idx & 255;
    A_[c][i] = tmp_h[codeL[c] * 256 + i];
  }
  __syncthreads();
  // h0 = seqFMA(concat(h_in, xhat) @ cc_w) + cc_b  -> B_
  {
    float acc[8] = {};
    for (int i = 0; i < 256; ++i) {
      const float w = cc_w[i * 256 + t];
#pragma unroll
      for (int c = 0; c < 8; ++c) acc[c] = __builtin_fmaf(A_[c][i], w, acc[c]);
    }
    for (int d = 0; d < 128; ++d) {
      const float w = cc_w[(256 + d) * 256 + t];
#pragma unroll
      for (int c = 0; c < 8; ++c) acc[c] = __builtin_fmaf(xhL[c][d], w, acc[c]);
    }
    const float b = cc_b[t];
#pragma unroll
    for (int c = 0; c < 8; ++c) B_[c][t] = __fadd_rn(acc[c], b);
  }
  __syncthreads();
  // r1 = relu(seqFMA(h0 @ w1_0) + b1_0) -> C_
  {
    float acc[8] = {};
    for (int i = 0; i < 256; ++i) {
      const float w = rb_w1[i * 256 + t];
#pragma unroll
      for (int c = 0; c < 8; ++c) acc[c] = __builtin_fmaf(B_[c][i], w, acc[c]);
    }
    const float b = rb_b1[t];
#pragma unroll
    for (int c = 0; c < 8; ++c) C_[c][t] = fmaxf(__fadd_rn(acc[c], b), 0.f);
  }
  __syncthreads();
  // h1 = (h0 + seqFMA(r1 @ w2_0)) + b2_0 -> A_
  {
    float acc[8] = {};
    for (int i = 0; i < 256; ++i) {
      const float w = rb_w2[i * 256 + t];
#pragma unroll
      for (int c = 0; c < 8; ++c) acc[c] = __builtin_fmaf(C_[c][i], w, acc[c]);
    }
    const float b = rb_b2[t];
#pragma unroll
    for (int c = 0; c < 8; ++c)
      A_[c][t] = __fadd_rn(__fadd_rn(B_[c][t], acc[c]), b);
  }
  __syncthreads();
  // r2 = relu(seqFMA(h1 @ w1_1) + b1_1) -> B_
  {
    float acc[8] = {};
    const float* w11 = rb_w1 + 65536;
    for (int i = 0; i < 256; ++i) {
      const float w = w11[i * 256 + t];
#pragma unroll
      for (int c = 0; c < 8; ++c) acc[c] = __builtin_fmaf(A_[c][i], w, acc[c]);
    }
    const float b = rb_b1[256 + t];
#pragma unroll
    for (int c = 0; c < 8; ++c) B_[c][t] = fmaxf(__fadd_rn(acc[c], b), 0.f);
  }
  __syncthreads();
  // h2 = (h1 + seqFMA(r2 @ w2_1)) + b2_1 -> C_
  {
    float acc[8] = {};
    const float* w21 = rb_w2 + 65536;
    for (int i = 0; i < 256; ++i) {
      const float w = w21[i * 256 + t];
#pragma unroll
      for (int c = 0; c < 8; ++c) acc[c] = __builtin_fmaf(B_[c][i], w, acc[c]);
    }
    const float b = rb_b2[256 + t];
#pragma unroll
    for (int c = 0; c < 8; ++c)
      C_[c][t] = __fadd_rn(__fadd_rn(A_[c][t], acc[c]), b);
  }
  __syncthreads();
  // cand = ((seqFMA(h2@out_w) + out_b) + cw_in) + xhat
  if (t < 128) {
    float acc[8] = {};
    for (int i = 0; i < 256; ++i) {
      const float w = out_w[i * 128 + t];
#pragma unroll
      for (int c = 0; c < 8; ++c) acc[c] = __builtin_fmaf(C_[c][i], w, acc[c]);
    }
    const float ob = out_b[t];
#pragma unroll
    for (int c = 0; c < 8; ++c) {
      const float cw_ = __fadd_rn(__fadd_rn(acc[c], ob), cbL[c][t]);
      const float cand = __fadd_rn(cw_, xhL[c][t]);
      candL[c][t] = cand;
      candv[(bb * 32 + j0 + c) * 128 + t] = cand;
    }
  }
  __syncthreads();
  if (t < 8) {
    float r[8];
#pragma unroll
    for (int j = 0; j < 8; ++j) {
      const float v = candL[t][j];
      r[j] = __fmul_rn(v, v);
    }
    for (int i = 8; i < 128; i += 8) {
#pragma unroll
      for (int j = 0; j < 8; ++j) {
        const float v = candL[t][i + j];
        r[j] = __fadd_rn(r[j], __fmul_rn(v, v));
      }
    }
    const float s1f = __fadd_rn(
        __fadd_rn(__fadd_rn(r[0], r[1]), __fadd_rn(r[2], r[3])),
        __fadd_rn(__fadd_rn(r[4], r[5]), __fadd_rn(r[6], r[7])));
    double s2 = 0.0;
    for (int d = 0; d < 128; ++d)
      s2 += (double)xqL[d] * (double)candL[t][d];
    const float s2f = (float)s2;
    d2r[bb * 32 + j0 + t] = __fsub_rn(s1f, __fmul_rn(2.0f, s2f));
  }
}

// ---------------- stage 3c/4: stable top-16 by f32 d2 ----------------
__global__ __launch_bounds__(64, 1) void k_final(
    const float* __restrict__ d2r, const int* __restrict__ sel32,
    const int* __restrict__ topc, const int* __restrict__ codes_in,
    const float* __restrict__ candv, float* __restrict__ out) {
  __shared__ u32 winLo[16];
  const int bb = blockIdx.x;
  const int t = threadIdx.x;
  u64 key = ~0ull;
  if (t < 32) {
    const u32 s = (u32)sel32[bb * 32 + t];
    key = ((u64)ordu(d2r[bb * 32 + t]) << 32) | (s << 5) | (u32)t;
  }
  for (int it = 0; it < 16; ++it) {
    u64 m = key;
#pragma unroll
    for (int sh = 1; sh < 64; sh <<= 1) {
      const u64 o = __shfl_xor(m, sh);
      m = (o < m) ? o : m;
    }
    if (key == m) key = ~0ull;
    if (t == 0) winLo[it] = (u32)(m & 0xFFFFFFFFu);
  }
  __syncthreads();
  if (t < 16) {
    const u32 lo = winLo[t];
    const int s = (int)((lo >> 5) & 511u);
    const int f = s >> 5;
    const int code = topc[(bb * 16 + f) * 32 + (s & 31)];
    float* oc = out + 512 * 16 * 128;
    oc[bb * 16 + t] = (float)codes_in[bb * 16 + f];
    oc[8192 + bb * 16 + t] = (float)codes_in[8192 + bb * 16 + f];
    oc[16384 + bb * 16 + t] = (float)code;
  }
  __syncthreads();
  for (int idx = t; idx < 2048; idx += 64) {
    const int w_ = idx >> 7, d = idx & 127;
    const int j = (int)(winLo[w_] & 31u);
    out[(bb * 16 + w_) * 128 + d] = candv[(bb * 32 + j) * 128 + d];
  }
}

// ---------------- launch ----------------
extern "C" void kernel_launch(void* const* d_in, const int* in_sizes, int n_in,
                              void* d_out, int out_size, void* d_ws,
                              size_t ws_size, hipStream_t stream) {
  const float* x = (const float*)d_in[0];
  const float* xhat = (const float*)d_in[1];
  const int* codes = (const int*)d_in[2];
  const float* cb = (const float*)d_in[3];
  const float* cbrq = (const float*)d_in[4];
  const float* in_w = (const float*)d_in[5];
  const float* in_b = (const float*)d_in[6];
  const float* cc_w = (const float*)d_in[7];
  const float* cc_b = (const float*)d_in[8];
  const float* rb_w1 = (const float*)d_in[9];
  const float* rb_b1 = (const float*)d_in[10];
  const float* rb_w2 = (const float*)d_in[11];
  const float* rb_b2 = (const float*)d_in[12];
  const float* out_w = (const float*)d_in[13];
  const float* out_b = (const float*)d_in[14];
  float* out = (float*)d_out;

  float* ws = (float*)d_ws;
  size_t o = 0;
  float* cb_sq = ws + o; o += 4096;
  float* xt = ws + o;    const size_t xt_off = o; o += (size_t)8192 * 128;
  float* cbT = ws + o;   o += (size_t)128 * 4096;
  float* tmp_h = ws + o; o += (size_t)4096 * 256;   // LIVE through k_rescore
  float* pc = ws + o;    const size_t pc_off = o; o += (size_t)4096 * 256;
  float* pb = ws + o;    o += (size_t)8192 * 256;
  float* A1 = ws + o;    o += (size_t)4096 * 256;
  float* A2 = ws + o;    o += (size_t)4096 * 256;
  float* Dc = ws + o;    o += (size_t)4096 * 128;
  float* B1 = ws + o;    o += (size_t)8192 * 256;
  float* B2 = ws + o;    o += (size_t)8192 * 256;
  float* Dr = ws + o;    o += (size_t)8192 * 128;
  float* W21 = ws + o;   o += 65536;
  float* V1 = ws + o;    o += 32768;
  float* V2 = ws + o;    o += 32768;
  float* bias2v = ws + o; o += 256;
  float* biasDv = ws + o; o += 128;
  int* topc = (int*)(ws + o); o += 262144;
  float* d2g = ws + o;   o += 262144;
  float* d2r = ws + xt_off;
  int* sel32 = (int*)(ws + xt_off + 16384);
  float* candv = ws + pc_off;

  k_cbrqT<<<dim3(128), dim3(256), 0, stream>>>(cbrq, cbT);
  k_cbsq<<<dim3(16), dim3(256), 0, stream>>>(cbT, cb_sq);
  k_xt<<<dim3(1024), dim3(256), 0, stream>>>(x, xhat, xt);
  k_biasprep<<<dim3(1), dim3(256), 0, stream>>>(rb_b1, rb_b2, rb_w1, out_w,
                                                out_b, bias2v, biasDv);
  k_codeh<<<dim3(4096), dim3(256), 0, stream>>>(cb, in_w, in_b, tmp_h);
  gemm_f32<<<dim3(64, 4), dim3(256), 0, stream>>>(tmp_h, cc_w, pc, 4096, 256,
                                                  256, nullptr, nullptr);
  gemm_f32<<<dim3(128, 4), dim3(256), 0, stream>>>(xhat, cc_w + 256 * 256, pb,
                                                   8192, 256, 128, cc_b,
                                                   nullptr);
  gemm_f32<<<dim3(64, 4), dim3(256), 0, stream>>>(pc, rb_w1, A1, 4096, 256, 256,
                                                  nullptr, nullptr);
  gemm_f32<<<dim3(64, 4), dim3(256), 0, stream>>>(pc, rb_w1 + 65536, A2, 4096,
                                                  256, 256, nullptr, nullptr);
  gemm_f32<<<dim3(64, 2), dim3(256), 0, stream>>>(pc, out_w, Dc, 4096, 128, 256,
                                                  nullptr, cb);
  gemm_f32<<<dim3(128, 4), dim3(256), 0, stream>>>(pb, rb_w1, B1, 8192, 256,
                                                   256, rb_b1, nullptr);
  gemm_f32<<<dim3(128, 4), dim3(256), 0, stream>>>(pb, rb_w1 + 65536, B2, 8192,
                                                   256, 256, bias2v, nullptr);
  gemm_f32<<<dim3(128, 2), dim3(256), 0, stream>>>(pb, out_w, Dr, 8192, 128,
                                                   256, biasDv, nullptr);
  gemm_f32<<<dim3(4, 4), dim3(256), 0, stream>>>(rb_w2, rb_w1 + 65536, W21, 256,
                                                 256, 256, nullptr, nullptr);
  gemm_f32<<<dim3(4, 2), dim3(256), 0, stream>>>(rb_w2, out_w, V1, 256, 128,
                                                 256, nullptr, nullptr);
  gemm_f32<<<dim3(4, 2), dim3(256), 0, stream>>>(rb_w2 + 65536, out_w, V2, 256,
                                                 128, 256, nullptr, nullptr);

  k_stage1<<<dim3(2048), dim3(512), 0, stream>>>(xt, cbT, cb_sq, topc);
  k_mlp<<<dim3(4096), dim3(512), 0, stream>>>(topc, A1, A2, Dc, B1, B2, Dr, W21,
                                              V1, V2, xhat, x, d2g);
  k_sel32<<<dim3(512), dim3(64), 0, stream>>>(d2g, sel32);
  k_rescore<<<dim3(2048), dim3(256), 0, stream>>>(
      sel32, topc, tmp_h, cb, xhat, x, cc_w, cc_b, rb_w1, rb_b1, rb_w2, rb_b2,
      out_w, out_b, d2r, candv);
  k_final<<<dim3(512), dim3(64), 0, stream>>>(d2r, sel32, topc, codes, candv,
                                              out);
  (void)in_sizes; (void)n_in; (void)out_size; (void)ws_size;
}